// Round 14
// baseline (70.598 us; speedup 1.0000x reference)
//
#include <hip/hip_runtime.h>
#include <hip/hip_bf16.h>
#include <cstdint>

// PiNet: B=8192, I=12, O=512, DEG=4.
// R13: decoupled GEMM. foldfeat fuses fold (blocks 0-511) + M materialization
// (blocks 512-767, M[oct][8192][8] fp16). GEMM has zero gen work: A staged by
// global_load_lds DMA, B reg-prefetched 2-deep, counted vmcnt(4)+raw s_barrier
// per kt (DMA stays in flight across barriers). Padded-prefix t-layout kept.

#define NB 8192
#define NI 12
#define NO 512
#define TPAD 2112          // 33 * 64
#define NKT 33
#define NQ 528             // TPAD / 4
#define NOCT 264           // TPAD / 8

typedef __attribute__((ext_vector_type(8))) _Float16 f16x8;
typedef __attribute__((ext_vector_type(4))) float f32x4;

#define MFMA16(a, b, c) __builtin_amdgcn_mfma_f32_16x16x32_f16(a, b, c, 0, 0, 0)

__device__ __forceinline__ int ceil4(int n) { return (n + 3) & ~3; }
__device__ __forceinline__ int H2f(int n) { return n * (n + 1) / 2; }
__device__ __forceinline__ int rank2(int a, int b) {
    int r = 0;
    for (int j = 0; j < a; ++j) r += NI - j;
    return r + (b - a);
}
__device__ __forceinline__ unsigned short f2h(float f) {
    _Float16 h = (_Float16)f;
    return __builtin_bit_cast(unsigned short, h);
}

// Layout bases: [0,16) deg<=1; [16,112) deg2; [112,608) deg3; [608,2108) deg4.
#define BASE2 16
#define BASE3 112
#define BASE4 608
#define TEND 2108

// ---------- maps: fd/rkA (fold descriptors), qd (gen quads), mq2 (msm pairs) --
__global__ __launch_bounds__(256) void pinet_maps(
    uint32_t* __restrict__ fd, float* __restrict__ rkA,
    uint32_t* __restrict__ qd, uint32_t* __restrict__ mq2) {
    int id = blockIdx.x * 256 + threadIdx.x;
    if (id < TPAD) {
        int t = id;
        uint32_t f = 7u << 16; float rk = 0.0f;
        if (t == 0) { f = 0u; rk = 1.0f; }
        else if (t < 13) { f = (1u << 16) | (uint32_t)(t - 1); rk = 1.0f; }
        else if (t < BASE2) { /* pad */ }
        else if (t < BASE3) {
            int base = BASE2;
            for (int a = 0; a < 12; ++a) {
                int L = ceil4(12 - a);
                if (t < base + L) {
                    int p = t - base;
                    if (p < 12 - a) {
                        int b = a + p;
                        f = (2u << 16) | (uint32_t)a | ((uint32_t)b << 4);
                        rk = (a == b) ? 0.5f : 1.0f;
                    }
                    break;
                }
                base += L;
            }
        } else if (t < BASE4) {
            int base = BASE3; bool done = false;
            for (int a = 0; a < 12 && !done; ++a)
                for (int b = a; b < 12; ++b) {
                    int L = ceil4(12 - b);
                    if (t < base + L) {
                        int p = t - base;
                        if (p < 12 - b) {
                            int c = b + p;
                            f = (3u << 16) | (uint32_t)a | ((uint32_t)b << 4) |
                                ((uint32_t)c << 8);
                            int k = 1, run = 1;
                            if (b == a) { ++run; k *= run; } else run = 1;
                            if (c == b) { ++run; k *= run; } else run = 1;
                            rk = 1.0f / (float)k;
                        }
                        done = true; break;
                    }
                    base += L;
                }
        } else if (t < TEND) {
            int base = BASE4; bool done = false;
            for (int a = 0; a < 12 && !done; ++a)
                for (int b = a; b < 12; ++b) {
                    int L = ceil4(H2f(12 - b));
                    if (t < base + L) {
                        int p = t - base;
                        if (p < H2f(12 - b)) {
                            int c = b;
                            while (p >= 12 - c) { p -= 12 - c; ++c; }
                            int d = c + p;
                            f = (4u << 16) | (uint32_t)a | ((uint32_t)b << 4) |
                                ((uint32_t)c << 8) | ((uint32_t)d << 12);
                            int k = 1, run = 1;
                            if (b == a) { ++run; k *= run; } else run = 1;
                            if (c == b) { ++run; k *= run; } else run = 1;
                            if (d == c) { ++run; k *= run; } else run = 1;
                            rk = 1.0f / (float)k;
                        }
                        done = true; break;
                    }
                    base += L;
                }
        }
        fd[t] = f; rkA[t] = rk;
        return;
    }
    id -= TPAD;
    if (id < NQ) {                       // quad descriptors: off1 | off2_0<<8
        int t0 = id * 4;
        uint32_t o1 = 0, o2 = 0;
        if (t0 < 16) {
            o1 = 0; o2 = (uint32_t)t0;
        } else if (t0 < BASE3) {
            int base = BASE2;
            for (int a = 0; a < 12; ++a) {
                int L = ceil4(12 - a);
                if (t0 < base + L) { o1 = 1 + a; o2 = 1 + a + (t0 - base); break; }
                base += L;
            }
        } else if (t0 < BASE4) {
            int base = BASE3; bool done = false;
            for (int a = 0; a < 12 && !done; ++a)
                for (int b = a; b < 12; ++b) {
                    int L = ceil4(12 - b);
                    if (t0 < base + L) {
                        o1 = 13 + rank2(a, b); o2 = 1 + b + (t0 - base);
                        done = true; break;
                    }
                    base += L;
                }
        } else if (t0 < TEND) {
            int base = BASE4; bool done = false;
            for (int a = 0; a < 12 && !done; ++a)
                for (int b = a; b < 12; ++b) {
                    int L = ceil4(H2f(12 - b));
                    if (t0 < base + L) {
                        o1 = 13 + rank2(a, b);
                        o2 = 13 + rank2(b, b) + (t0 - base);
                        done = true; break;
                    }
                    base += L;
                }
        }
        qd[id] = o1 | (o2 << 8);
        return;
    }
    id -= NQ;
    if (id < 78) {                       // deg2 msm build pairs
        int r = id;
        int a = 0; while (r >= (NI - a)) { r -= (NI - a); ++a; }
        int b = a + r;
        mq2[id] = (uint32_t)(1 + a) | ((uint32_t)(1 + b) << 16);
    }
}

// ---------- foldfeat: blocks [0,512) fold; blocks [512,768) materialize M ----
__global__ __launch_bounds__(1024) void pinet_foldfeat(
    const float* __restrict__ w0, const float* __restrict__ w1,
    const float* __restrict__ w2, const float* __restrict__ w3,
    const float* __restrict__ w4,
    const uint32_t* __restrict__ fd, const float* __restrict__ rkA,
    const float* __restrict__ x, const uint32_t* __restrict__ qd,
    const uint32_t* __restrict__ mq2,
    ushort* __restrict__ Wh, ushort* __restrict__ M) {
    __shared__ float sbuf[22608];        // 90,432 B, overlaid per role
    const int tid = threadIdx.x;

    if (blockIdx.x < NO) {
        // ----- fold: o = blockIdx.x (identical math to R12) -----
        float* sw4 = sbuf;               // 20736
        float* sw3 = sbuf + 20736;       // 1728
        float* sw2 = sbuf + 22464;       // 144
        const int o = blockIdx.x;
        {
            const float4* g4 = (const float4*)(w4 + o * 20736);
            float4* s4 = (float4*)sw4;
            for (int i = tid; i < 5184; i += 1024) s4[i] = g4[i];
            if (tid < 432) ((float4*)sw3)[tid] = ((const float4*)(w3 + o * 1728))[tid];
            if (tid < 36)  ((float4*)sw2)[tid] = ((const float4*)(w2 + o * 144))[tid];
        }
        __syncthreads();
#define W4P(p, q, r, s_) sw4[(p) * 1728 + (q) * 144 + (r) * 12 + (s_)]
#define W3P(p, q, r)     sw3[(p) * 144 + (q) * 12 + (r)]
        for (int t = tid; t < TPAD; t += 1024) {
            uint32_t f = fd[t];
            int deg = (f >> 16) & 7;
            int a = f & 15, b = (f >> 4) & 15, c = (f >> 8) & 15, d = (f >> 12) & 15;
            float s = 0.0f;
            if (deg == 0) {
                s = w0[o];
            } else if (deg == 1) {
                s = w1[o * 12 + a];
            } else if (deg == 2) {
                s = (sw2[a * 12 + b] + sw2[b * 12 + a]) * rkA[t];
            } else if (deg == 3) {
                s = (W3P(a, b, c) + W3P(a, c, b) + W3P(b, a, c) +
                     W3P(b, c, a) + W3P(c, a, b) + W3P(c, b, a)) * rkA[t];
            } else if (deg == 4) {
                float s4v =
                    W4P(a,b,c,d) + W4P(a,b,d,c) + W4P(a,c,b,d) + W4P(a,c,d,b) +
                    W4P(a,d,b,c) + W4P(a,d,c,b) + W4P(b,a,c,d) + W4P(b,a,d,c) +
                    W4P(b,c,a,d) + W4P(b,c,d,a) + W4P(b,d,a,c) + W4P(b,d,c,a) +
                    W4P(c,a,b,d) + W4P(c,a,d,b) + W4P(c,b,a,d) + W4P(c,b,d,a) +
                    W4P(c,d,a,b) + W4P(c,d,b,a) + W4P(d,a,b,c) + W4P(d,a,c,b) +
                    W4P(d,b,a,c) + W4P(d,b,c,a) + W4P(d,c,a,b) + W4P(d,c,b,a);
                s = s4v * rkA[t];
            }
            Wh[((t >> 3) * NO + o) * 8 + (t & 7)] = f2h(s);
        }
#undef W4P
#undef W3P
    } else {
        // ----- mfeat: b0 = (blockIdx.x - 512) * 32, 32 batches, all 264 octs --
        float* msm = sbuf;                         // 32*97 = 3104 floats
        uint32_t* qd_sh = (uint32_t*)(sbuf + 3104); // 528 u32
        const int b0 = (blockIdx.x - NO) * 32;

        for (int idx = tid; idx < 32 * 12; idx += 1024) {
            int b = idx / 12, j = idx % 12;
            msm[b * 97 + 1 + j] = x[(b0 + b) * 12 + j];
        }
        if (tid < 32) msm[tid * 97] = 1.0f;
        if (tid >= 64 && tid < 256) {
            int idx = tid - 64;                    // 32*6 zero-pad slots
            int b = idx / 6, j = idx % 6;
            msm[b * 97 + 91 + j] = 0.0f;
        }
        for (int i = tid; i < NQ; i += 1024) qd_sh[i] = qd[i];
        __syncthreads();
        for (int idx = tid; idx < 32 * 78; idx += 1024) {
            int b = idx / 78, q = idx % 78;
            uint32_t m2 = mq2[q];
            msm[b * 97 + 13 + q] = msm[b * 97 + (m2 & 0xFFFFu)] *
                                   msm[b * 97 + (m2 >> 16)];
        }
        __syncthreads();

        const int bl = tid & 31, task = tid >> 5;  // 32 tasks over octs
        const float* row = &msm[bl * 97];
        for (int oct = task; oct < NOCT; oct += 32) {
            uint32_t d0 = qd_sh[2 * oct], d1 = qd_sh[2 * oct + 1];
            float m1a = row[d0 & 0xFFu]; int o2a = (d0 >> 8) & 0xFFu;
            float m1b = row[d1 & 0xFFu]; int o2b = (d1 >> 8) & 0xFFu;
            float p0 = m1a * row[o2a + 0], p1 = m1a * row[o2a + 1];
            float p2 = m1a * row[o2a + 2], p3 = m1a * row[o2a + 3];
            float p4 = m1b * row[o2b + 0], p5 = m1b * row[o2b + 1];
            float p6 = m1b * row[o2b + 2], p7 = m1b * row[o2b + 3];
            uint32_t k0 = (uint32_t)f2h(p0) | ((uint32_t)f2h(p1) << 16);
            uint32_t k1 = (uint32_t)f2h(p2) | ((uint32_t)f2h(p3) << 16);
            uint32_t k2 = (uint32_t)f2h(p4) | ((uint32_t)f2h(p5) << 16);
            uint32_t k3 = (uint32_t)f2h(p6) | ((uint32_t)f2h(p7) << 16);
            *(uint4*)&M[((size_t)oct * NB + b0 + bl) * 8] = make_uint4(k0, k1, k2, k3);
        }
    }
}

// ---------- MFMA GEMM: out[b,o] = sum_t M[t][b] * Wt[t][o], fp16 ----------
// Block: 64 b x 256 o, 512 threads (8 waves, each 64b x 32o). Grid 256.
// A via global_load_lds DMA (wave wv stages oct wv); B reg-prefetched 2-deep.
// Counted vmcnt + raw s_barrier per kt: next DMA stays in flight.
__global__ __launch_bounds__(512) void pinet_gemm(
    const ushort* __restrict__ M, const ushort* __restrict__ Wh,
    float* __restrict__ out) {
    __shared__ ushort Ash[2][8][64][8];   // [buf][oct][b][8 fp16] = 16 KB

    const int tid = threadIdx.x;
    const int b0 = (blockIdx.x >> 1) * 64;
    const int blkO = blockIdx.x & 1;
    const int l = tid & 63, wv = tid >> 6;
    const int lm = l & 15, lg = l >> 4;
    const int o_w = blkO * 256 + wv * 32;

    f32x4 acc[4][2] = {};                 // [bs][os]
    f16x8 B0[2][2], B1[2][2];             // [c][os]

    auto DMA = [&](int kt, int buf) {
        const uint32_t* src = (const uint32_t*)
            (M + (((size_t)(kt * 8 + wv)) * NB + b0 + l) * 8);
        __builtin_amdgcn_global_load_lds(
            (const __attribute__((address_space(1))) uint32_t*)src,
            (__attribute__((address_space(3))) uint32_t*)&Ash[buf][wv][0][0],
            16, 0, 0);
    };
    auto loadB = [&](int kt, f16x8 (&B)[2][2]) {
#pragma unroll
        for (int c = 0; c < 2; ++c)
#pragma unroll
            for (int os = 0; os < 2; ++os) {
                int pk = kt * 8 + c * 4 + lg;
                B[c][os] = *(const f16x8*)
                    (Wh + ((size_t)pk * NO + o_w + os * 16 + lm) * 8);
            }
    };
    auto mfmaR = [&](int buf, f16x8 (&B)[2][2]) {
#pragma unroll
        for (int c = 0; c < 2; ++c) {
            f16x8 a0 = *(const f16x8*)&Ash[buf][c * 4 + lg][0 * 16 + lm][0];
            f16x8 a1 = *(const f16x8*)&Ash[buf][c * 4 + lg][1 * 16 + lm][0];
            f16x8 a2 = *(const f16x8*)&Ash[buf][c * 4 + lg][2 * 16 + lm][0];
            f16x8 a3 = *(const f16x8*)&Ash[buf][c * 4 + lg][3 * 16 + lm][0];
#pragma unroll
            for (int os = 0; os < 2; ++os) {
                acc[0][os] = MFMA16(a0, B[c][os], acc[0][os]);
                acc[1][os] = MFMA16(a1, B[c][os], acc[1][os]);
                acc[2][os] = MFMA16(a2, B[c][os], acc[2][os]);
                acc[3][os] = MFMA16(a3, B[c][os], acc[3][os]);
            }
        }
    };

    DMA(0, 0);
    loadB(0, B0);
    loadB(1, B1);

    for (int kt = 0; kt < NKT; ++kt) {
        // wait own DMA(kt); keep newer prefetches in flight
        if (kt == 0)            asm volatile("s_waitcnt vmcnt(8)" ::: "memory");
        else if (kt < NKT - 1)  asm volatile("s_waitcnt vmcnt(4)" ::: "memory");
        else                    asm volatile("s_waitcnt vmcnt(0)" ::: "memory");
        __builtin_amdgcn_s_barrier();     // all waves' DMA(kt) done; prev reads done
        __builtin_amdgcn_sched_barrier(0);
        if (kt + 1 < NKT) DMA(kt + 1, (kt + 1) & 1);
        if (kt & 1) {
            mfmaR(1, B1);
            if (kt + 2 < NKT) loadB(kt + 2, B1);
        } else {
            mfmaR(0, B0);
            if (kt + 2 < NKT) loadB(kt + 2, B0);
        }
        // reads of Ash[buf] complete before the MFMA that consumes them (lgkm
        // waits inserted by compiler); barrier at next iter top orders the
        // DMA(kt+2) overwrite of this buf after all waves' reads.
        if (kt + 1 < NKT) {
            asm volatile("s_waitcnt lgkmcnt(0)" ::: "memory");
        }
    }

#pragma unroll
    for (int bs = 0; bs < 4; ++bs)
#pragma unroll
        for (int os = 0; os < 2; ++os) {
            int ob = o_w + os * 16 + lm;
#pragma unroll
            for (int r = 0; r < 4; ++r) {
                int bb = b0 + bs * 16 + lg * 4 + r;
                out[bb * NO + ob] = acc[bs][os][r];
            }
        }
}

extern "C" void kernel_launch(void* const* d_in, const int* in_sizes, int n_in,
                              void* d_out, int out_size, void* d_ws, size_t ws_size,
                              hipStream_t stream) {
    const float* x  = (const float*)d_in[0];
    const float* w0 = (const float*)d_in[1];
    const float* w1 = (const float*)d_in[2];
    const float* w2 = (const float*)d_in[3];
    const float* w3 = (const float*)d_in[4];
    const float* w4 = (const float*)d_in[5];
    float* out = (float*)d_out;

    uint8_t* ws = (uint8_t*)d_ws;
    uint32_t* qd  = (uint32_t*)ws;                 // 2112 B  (pad 4096)
    uint32_t* mq2 = (uint32_t*)(ws + 4096);        // 312 B   (pad 512)
    uint32_t* fd  = (uint32_t*)(ws + 4608);        // 8448 B  (pad 8704)
    float*    rkA = (float*)(ws + 13312);          // 8448 B  (pad 8704)
    ushort*   Wh  = (ushort*)(ws + 22016);         // 264*512*8*2 = 2,162,688 B
    ushort*   Mm  = (ushort*)(ws + 22016 + 2162688); // 264*8192*8*2 = 34,603,008 B

    pinet_maps<<<11, 256, 0, stream>>>(fd, rkA, qd, mq2);
    pinet_foldfeat<<<NO + NB / 32, 1024, 0, stream>>>(
        w0, w1, w2, w3, w4, fd, rkA, x, qd, mq2, Wh, Mm);
    pinet_gemm<<<(NB / 64) * 2, 512, 0, stream>>>(Mm, Wh, out);
}

// Round 15
// 52.393 us; speedup vs baseline: 1.3475x; 1.3475x over previous
//
#include <hip/hip_runtime.h>
#include <hip/hip_bf16.h>
#include <cstdint>

// PiNet: B=8192, I=12, O=512, DEG=4.
// R14: consolidate to the empirically best structure (R6, 57.6us): compact
// t-layout TPAD=1856, f32-staged orbit-gather fold, 16-wave fused-gen gemm
// with mp descriptors read from L2. NEW: all tables computed at COMPILE TIME
// (constexpr -> device rodata) -- the maps kernel and its launch gap are gone.

#define NB 8192
#define NI 12
#define NO 512
#define T_TOTAL 1820
#define TPAD 1856          // 29 * 64
#define NKT 29
#define B2 13
#define B3 91
#define B4 455

typedef __attribute__((ext_vector_type(8))) _Float16 f16x8;
typedef __attribute__((ext_vector_type(4))) float f32x4;

#define MFMA16(a, b, c) __builtin_amdgcn_mfma_f32_16x16x32_f16(a, b, c, 0, 0, 0)

__device__ __forceinline__ unsigned short f2h(float f) {
    _Float16 h = (_Float16)f;
    return __builtin_bit_cast(unsigned short, h);
}

// ---------- compile-time tables ----------
constexpr int H2c(int n) { return n * (n + 1) / 2; }
constexpr int H3c(int n) { return n * (n + 1) * (n + 2) / 6; }
constexpr int rank2c(int a, int b) {
    int r = 0;
    for (int j = 0; j < a; ++j) r += NI - j;
    return r + (b - a);
}

// mp[t] = off1 | off2<<16 : monomial value = msm[off1] * msm[off2]
struct alignas(16) MPArr { uint32_t v[TPAD]; };
constexpr MPArr gen_mp() {
    MPArr m{};
    for (int t = 0; t < TPAD; ++t) {
        uint32_t v = 0;
        if (t == 0) {
            v = 0;
        } else if (t < B2) {
            v = (uint32_t)t;
        } else if (t < B3) {
            int r = t - B2, a = 0;
            while (r >= NI - a) { r -= NI - a; ++a; }
            int b = a + r;
            v = (uint32_t)(1 + a) | ((uint32_t)(1 + b) << 16);
        } else if (t < B4) {
            int r = t - B3, a = 0;
            while (r >= H2c(NI - a)) { r -= H2c(NI - a); ++a; }
            int b = a;
            while (r >= NI - b) { r -= NI - b; ++b; }
            int c = b + r;
            v = (uint32_t)(13 + rank2c(a, b)) | ((uint32_t)(1 + c) << 16);
        } else if (t < T_TOTAL) {
            int r = t - B4, a = 0;
            while (r >= H3c(NI - a)) { r -= H3c(NI - a); ++a; }
            int b = a;
            while (r >= H2c(NI - b)) { r -= H2c(NI - b); ++b; }
            int c = b;
            while (r >= NI - c) { r -= NI - c; ++c; }
            int d = c + r;
            v = (uint32_t)(13 + rank2c(a, b)) | ((uint32_t)(13 + rank2c(c, d)) << 16);
        }
        m.v[t] = v;          // t in [1820,1856): monomial = 1, weight 0
    }
    return m;
}
__device__ constexpr MPArr MP = gen_mp();

// fold orbit descriptors: sorted tuple (4b/idx) + 1/prod(run-length!)
struct FoldArr {
    uint16_t tup2[78];  float rk2[78];
    uint16_t tup3[364]; float rk3[364];
    uint16_t tup4[1368]; float rk4[1368];
};
constexpr FoldArr gen_fold() {
    FoldArr f{};
    for (int q = 0; q < 78; ++q) {
        int r = q, a = 0;
        while (r >= NI - a) { r -= NI - a; ++a; }
        int b = a + r;
        f.tup2[q] = (uint16_t)(a | (b << 4));
        f.rk2[q] = (a == b) ? 0.5f : 1.0f;
    }
    for (int q = 0; q < 364; ++q) {
        int r = q, a = 0;
        while (r >= H2c(NI - a)) { r -= H2c(NI - a); ++a; }
        int b = a;
        while (r >= NI - b) { r -= NI - b; ++b; }
        int c = b + r;
        f.tup3[q] = (uint16_t)(a | (b << 4) | (c << 8));
        int k = 1, run = 1;
        if (b == a) { ++run; k *= run; } else run = 1;
        if (c == b) { ++run; k *= run; } else run = 1;
        f.rk3[q] = 1.0f / (float)k;
    }
    for (int q = 0; q < 1365; ++q) {
        int r = q, a = 0;
        while (r >= H3c(NI - a)) { r -= H3c(NI - a); ++a; }
        int b = a;
        while (r >= H2c(NI - b)) { r -= H2c(NI - b); ++b; }
        int c = b;
        while (r >= NI - c) { r -= NI - c; ++c; }
        int d = c + r;
        f.tup4[q] = (uint16_t)(a | (b << 4) | (c << 8) | (d << 12));
        int k = 1, run = 1;
        if (b == a) { ++run; k *= run; } else run = 1;
        if (c == b) { ++run; k *= run; } else run = 1;
        if (d == c) { ++run; k *= run; } else run = 1;
        f.rk4[q] = 1.0f / (float)k;
    }
    return f;
}
__device__ constexpr FoldArr FT = gen_fold();

// ---------- fold: stage weight row in LDS (f32), per-t orbit gather ----------
// One block (1024 threads) per o. Wh fp16 pack-of-8: [((t>>3)*512+o)*8+(t&7)].
__global__ __launch_bounds__(1024) void pinet_fold(
    const float* __restrict__ w0, const float* __restrict__ w1,
    const float* __restrict__ w2, const float* __restrict__ w3,
    const float* __restrict__ w4, ushort* __restrict__ Wh) {
    __shared__ float sw4[20736];
    __shared__ float sw3[1728];
    __shared__ float sw2[144];
    const int tid = threadIdx.x;
    const int o = blockIdx.x;

    {   // coalesced staging
        const float4* g4 = (const float4*)(w4 + o * 20736);
        float4* s4 = (float4*)sw4;
        for (int i = tid; i < 5184; i += 1024) s4[i] = g4[i];
        if (tid < 432) ((float4*)sw3)[tid] = ((const float4*)(w3 + o * 1728))[tid];
        if (tid < 36)  ((float4*)sw2)[tid] = ((const float4*)(w2 + o * 144))[tid];
    }
    __syncthreads();

#define W4P(p, q, r, s_) sw4[(p) * 1728 + (q) * 144 + (r) * 12 + (s_)]
#define W3P(p, q, r)     sw3[(p) * 144 + (q) * 12 + (r)]
    for (int t = tid; t < TPAD; t += 1024) {
        float s = 0.0f;
        if (t == 0) {
            s = w0[o];
        } else if (t < B2) {
            s = w1[o * 12 + (t - 1)];
        } else if (t < B3) {
            int q = t - B2; int tp = FT.tup2[q];
            int a = tp & 15, b = (tp >> 4) & 15;
            s = (sw2[a * 12 + b] + sw2[b * 12 + a]) * FT.rk2[q];
        } else if (t < B4) {
            int q = t - B3; int tp = FT.tup3[q];
            int a = tp & 15, b = (tp >> 4) & 15, c = (tp >> 8) & 15;
            s = (W3P(a, b, c) + W3P(a, c, b) + W3P(b, a, c) +
                 W3P(b, c, a) + W3P(c, a, b) + W3P(c, b, a)) * FT.rk3[q];
        } else if (t < T_TOTAL) {
            int q = t - B4; int tp = FT.tup4[q];
            int a = tp & 15, b = (tp >> 4) & 15, c = (tp >> 8) & 15, d = (tp >> 12) & 15;
            float s4v =
                W4P(a,b,c,d) + W4P(a,b,d,c) + W4P(a,c,b,d) + W4P(a,c,d,b) +
                W4P(a,d,b,c) + W4P(a,d,c,b) + W4P(b,a,c,d) + W4P(b,a,d,c) +
                W4P(b,c,a,d) + W4P(b,c,d,a) + W4P(b,d,a,c) + W4P(b,d,c,a) +
                W4P(c,a,b,d) + W4P(c,a,d,b) + W4P(c,b,a,d) + W4P(c,b,d,a) +
                W4P(c,d,a,b) + W4P(c,d,b,a) + W4P(d,a,b,c) + W4P(d,a,c,b) +
                W4P(d,b,a,c) + W4P(d,b,c,a) + W4P(d,c,a,b) + W4P(d,c,b,a);
            s = s4v * FT.rk4[q];
        }
        Wh[((t >> 3) * NO + o) * 8 + (t & 7)] = f2h(s);
    }
#undef W4P
#undef W3P
}

// ---------- MFMA GEMM: out[b,o] = sum_t M[t][b] * Wt[t][o], fp16 ----------
// Block: 64 b x 256 o, 1024 threads (16 waves = 2wB x 8wO), wave 32b x 32o,
// KT=64. A generated on the fly into double-buffered swizzled LDS; B direct
// from L2, reg double-buffered. (Exact R6 structure, mp from rodata.)
__global__ __launch_bounds__(1024, 4) void pinet_gemm(
    const float* __restrict__ x, const ushort* __restrict__ Wh,
    float* __restrict__ out) {
    __shared__ float msm[64][93];           // per-b: {1, x0..x11, 78 deg2}
    __shared__ ushort Ash[2][64][8][8];     // [buf][b][t-octet slot (swz)][8 fp16]

    const int tid = threadIdx.x;
    const int blkB = blockIdx.x >> 1;
    const int blkO = blockIdx.x & 1;
    const int b0 = blkB * 64;

    for (int idx = tid; idx < 64 * 13; idx += 1024) {
        int b = idx / 13, j = idx % 13;
        msm[b][j] = (j == 0) ? 1.0f : x[(b0 + b) * 12 + (j - 1)];
    }
    __syncthreads();
    for (int idx = tid; idx < 64 * 78; idx += 1024) {
        int b = idx / 78, q = idx % 78;
        uint32_t m2 = MP.v[B2 + q];
        msm[b][13 + q] = msm[b][m2 & 0xFFFFu] * msm[b][m2 >> 16];
    }

    const int l = tid & 63, w = tid >> 6;   // 16 waves
    const int lm = l & 15, lg = l >> 4;
    const int wB = w >> 3, wO = w & 7;      // 2 b-halves x 8 o-groups
    const int o_w = blkO * 256 + wO * 32;
    const int bgen = tid & 63;
    const int task = tid >> 6;              // 0..15, 4 t's each
    const int sA = (task >> 1) ^ (bgen & 7);
    const int hOf = (task & 1) * 4;

    f32x4 acc[2][2] = {};
    f16x8 B0[2][2], B1[2][2];               // [os][chunk]

    auto gen = [&](int kt, int buf) {
        int t0 = kt * 64 + task * 4;
        uint4 mq = *(const uint4*)&MP.v[t0];
        const float* row = msm[bgen];
        uint32_t mqs[4] = {mq.x, mq.y, mq.z, mq.w};
        ushort4 v;
        unsigned short vv[4];
#pragma unroll
        for (int j = 0; j < 4; ++j) {
            float p = row[mqs[j] & 0xFFFFu] * row[mqs[j] >> 16];
            vv[j] = f2h(p);
        }
        v.x = vv[0]; v.y = vv[1]; v.z = vv[2]; v.w = vv[3];
        *(ushort4*)&Ash[buf][bgen][sA][hOf] = v;
    };
    auto loadB = [&](int kt, f16x8 (&B)[2][2]) {
#pragma unroll
        for (int os = 0; os < 2; ++os)
#pragma unroll
            for (int c = 0; c < 2; ++c) {
                int pk = kt * 8 + c * 4 + lg;
                B[os][c] = *(const f16x8*)(Wh + (pk * NO + o_w + os * 16 + lm) * 8);
            }
    };
    auto mfmaR = [&](int cur, f16x8 (&B)[2][2]) {
#pragma unroll
        for (int c = 0; c < 2; ++c) {
            f16x8 a[2];
#pragma unroll
            for (int bs = 0; bs < 2; ++bs) {
                int br = wB * 32 + bs * 16 + lm;
                a[bs] = *(const f16x8*)&Ash[cur][br][(c * 4 + lg) ^ (br & 7)][0];
            }
#pragma unroll
            for (int bs = 0; bs < 2; ++bs)
#pragma unroll
                for (int os = 0; os < 2; ++os)
                    acc[bs][os] = MFMA16(a[bs], B[os][c], acc[bs][os]);
        }
    };

    __syncthreads();          // msm ready
    gen(0, 0);
    loadB(0, B0);
    __syncthreads();          // Ash[0] ready

    for (int kt2 = 0; kt2 < 28; kt2 += 2) {
        loadB(kt2 + 1, B1);
        gen(kt2 + 1, 1);
        mfmaR(0, B0);
        __syncthreads();
        loadB(kt2 + 2, B0);   // kt2+2 <= 28 < NKT always
        gen(kt2 + 2, 0);
        mfmaR(1, B1);
        __syncthreads();
    }
    mfmaR(0, B0);             // kt = 28

#pragma unroll
    for (int bs = 0; bs < 2; ++bs)
#pragma unroll
        for (int os = 0; os < 2; ++os) {
            int ob = o_w + os * 16 + lm;
#pragma unroll
            for (int r = 0; r < 4; ++r) {
                int bb = b0 + wB * 32 + bs * 16 + lg * 4 + r;
                out[bb * NO + ob] = acc[bs][os][r];
            }
        }
}

extern "C" void kernel_launch(void* const* d_in, const int* in_sizes, int n_in,
                              void* d_out, int out_size, void* d_ws, size_t ws_size,
                              hipStream_t stream) {
    const float* x  = (const float*)d_in[0];
    const float* w0 = (const float*)d_in[1];
    const float* w1 = (const float*)d_in[2];
    const float* w2 = (const float*)d_in[3];
    const float* w3 = (const float*)d_in[4];
    const float* w4 = (const float*)d_in[5];
    float* out = (float*)d_out;

    ushort* Wh = (ushort*)d_ws;            // 232*512*8*2 = 1,900,544 B

    pinet_fold<<<NO, 1024, 0, stream>>>(w0, w1, w2, w3, w4, Wh);
    pinet_gemm<<<(NB / 64) * 2, 1024, 0, stream>>>(x, Wh, out);
}

// Round 16
// 48.427 us; speedup vs baseline: 1.4578x; 1.0819x over previous
//
#include <hip/hip_runtime.h>
#include <hip/hip_bf16.h>
#include <cstdint>

// PiNet: B=8192, I=12, O=512, DEG=4.
// R15: gemm de-duplicated -- BB=32, full O=512 per block (grid 256 = 1/CU):
// each b-row's monomials generated ONCE (R14 generated them twice, once per
// o-half). Gen LDS instrs/kt halve; Ash 8KB; B/A traffic unchanged.
// Fold: fp16 LDS staging (44KB -> 2 blocks/CU, staging/gather overlap).

#define NB 8192
#define NI 12
#define NO 512
#define T_TOTAL 1820
#define TPAD 1856          // 29 * 64
#define NKT 29
#define B2 13
#define B3 91
#define B4 455

typedef __attribute__((ext_vector_type(8))) _Float16 f16x8;
typedef __attribute__((ext_vector_type(4))) float f32x4;

#define MFMA16(a, b, c) __builtin_amdgcn_mfma_f32_16x16x32_f16(a, b, c, 0, 0, 0)

__device__ __forceinline__ unsigned short f2h(float f) {
    _Float16 h = (_Float16)f;
    return __builtin_bit_cast(unsigned short, h);
}
__device__ __forceinline__ float h2f(unsigned short u) {
    return (float)__builtin_bit_cast(_Float16, u);
}

// ---------- compile-time tables ----------
constexpr int H2c(int n) { return n * (n + 1) / 2; }
constexpr int H3c(int n) { return n * (n + 1) * (n + 2) / 6; }
constexpr int rank2c(int a, int b) {
    int r = 0;
    for (int j = 0; j < a; ++j) r += NI - j;
    return r + (b - a);
}

struct alignas(16) MPArr { uint32_t v[TPAD]; };
constexpr MPArr gen_mp() {
    MPArr m{};
    for (int t = 0; t < TPAD; ++t) {
        uint32_t v = 0;
        if (t == 0) {
            v = 0;
        } else if (t < B2) {
            v = (uint32_t)t;
        } else if (t < B3) {
            int r = t - B2, a = 0;
            while (r >= NI - a) { r -= NI - a; ++a; }
            int b = a + r;
            v = (uint32_t)(1 + a) | ((uint32_t)(1 + b) << 16);
        } else if (t < B4) {
            int r = t - B3, a = 0;
            while (r >= H2c(NI - a)) { r -= H2c(NI - a); ++a; }
            int b = a;
            while (r >= NI - b) { r -= NI - b; ++b; }
            int c = b + r;
            v = (uint32_t)(13 + rank2c(a, b)) | ((uint32_t)(1 + c) << 16);
        } else if (t < T_TOTAL) {
            int r = t - B4, a = 0;
            while (r >= H3c(NI - a)) { r -= H3c(NI - a); ++a; }
            int b = a;
            while (r >= H2c(NI - b)) { r -= H2c(NI - b); ++b; }
            int c = b;
            while (r >= NI - c) { r -= NI - c; ++c; }
            int d = c + r;
            v = (uint32_t)(13 + rank2c(a, b)) | ((uint32_t)(13 + rank2c(c, d)) << 16);
        }
        m.v[t] = v;          // t in [1820,1856): monomial = 1, weight 0
    }
    return m;
}
__device__ constexpr MPArr MP = gen_mp();

struct FoldArr {
    uint16_t tup2[78];  float rk2[78];
    uint16_t tup3[364]; float rk3[364];
    uint16_t tup4[1368]; float rk4[1368];
};
constexpr FoldArr gen_fold() {
    FoldArr f{};
    for (int q = 0; q < 78; ++q) {
        int r = q, a = 0;
        while (r >= NI - a) { r -= NI - a; ++a; }
        int b = a + r;
        f.tup2[q] = (uint16_t)(a | (b << 4));
        f.rk2[q] = (a == b) ? 0.5f : 1.0f;
    }
    for (int q = 0; q < 364; ++q) {
        int r = q, a = 0;
        while (r >= H2c(NI - a)) { r -= H2c(NI - a); ++a; }
        int b = a;
        while (r >= NI - b) { r -= NI - b; ++b; }
        int c = b + r;
        f.tup3[q] = (uint16_t)(a | (b << 4) | (c << 8));
        int k = 1, run = 1;
        if (b == a) { ++run; k *= run; } else run = 1;
        if (c == b) { ++run; k *= run; } else run = 1;
        f.rk3[q] = 1.0f / (float)k;
    }
    for (int q = 0; q < 1365; ++q) {
        int r = q, a = 0;
        while (r >= H3c(NI - a)) { r -= H3c(NI - a); ++a; }
        int b = a;
        while (r >= H2c(NI - b)) { r -= H2c(NI - b); ++b; }
        int c = b;
        while (r >= NI - c) { r -= NI - c; ++c; }
        int d = c + r;
        f.tup4[q] = (uint16_t)(a | (b << 4) | (c << 8) | (d << 12));
        int k = 1, run = 1;
        if (b == a) { ++run; k *= run; } else run = 1;
        if (c == b) { ++run; k *= run; } else run = 1;
        if (d == c) { ++run; k *= run; } else run = 1;
        f.rk4[q] = 1.0f / (float)k;
    }
    return f;
}
__device__ constexpr FoldArr FT = gen_fold();

// ---------- fold: fp16 LDS staging (2 blocks/CU) + per-t orbit gather ----------
// One block (1024 threads) per o. Wh fp16 pack-of-8: [((t>>3)*512+o)*8+(t&7)].
__global__ __launch_bounds__(1024, 8) void pinet_fold(
    const float* __restrict__ w0, const float* __restrict__ w1,
    const float* __restrict__ w2, const float* __restrict__ w3,
    const float* __restrict__ w4, ushort* __restrict__ Wh) {
    __shared__ ushort sw4h[20736];
    __shared__ ushort sw3h[1728];
    __shared__ ushort sw2h[144];
    const int tid = threadIdx.x;
    const int o = blockIdx.x;

    {   // coalesced staging, f32 -> fp16
        const float4* g4 = (const float4*)(w4 + o * 20736);
        for (int i = tid; i < 5184; i += 1024) {
            float4 v = g4[i];
            ushort4 h = {f2h(v.x), f2h(v.y), f2h(v.z), f2h(v.w)};
            *(ushort4*)&sw4h[i * 4] = h;
        }
        if (tid < 432) {
            float4 v = ((const float4*)(w3 + o * 1728))[tid];
            ushort4 h = {f2h(v.x), f2h(v.y), f2h(v.z), f2h(v.w)};
            *(ushort4*)&sw3h[tid * 4] = h;
        }
        if (tid < 36) {
            float4 v = ((const float4*)(w2 + o * 144))[tid];
            ushort4 h = {f2h(v.x), f2h(v.y), f2h(v.z), f2h(v.w)};
            *(ushort4*)&sw2h[tid * 4] = h;
        }
    }
    __syncthreads();

#define W4P(p, q, r, s_) h2f(sw4h[(p) * 1728 + (q) * 144 + (r) * 12 + (s_)])
#define W3P(p, q, r)     h2f(sw3h[(p) * 144 + (q) * 12 + (r)])
    for (int t = tid; t < TPAD; t += 1024) {
        float s = 0.0f;
        if (t == 0) {
            s = w0[o];
        } else if (t < B2) {
            s = w1[o * 12 + (t - 1)];
        } else if (t < B3) {
            int q = t - B2; int tp = FT.tup2[q];
            int a = tp & 15, b = (tp >> 4) & 15;
            s = (h2f(sw2h[a * 12 + b]) + h2f(sw2h[b * 12 + a])) * FT.rk2[q];
        } else if (t < B4) {
            int q = t - B3; int tp = FT.tup3[q];
            int a = tp & 15, b = (tp >> 4) & 15, c = (tp >> 8) & 15;
            s = (W3P(a, b, c) + W3P(a, c, b) + W3P(b, a, c) +
                 W3P(b, c, a) + W3P(c, a, b) + W3P(c, b, a)) * FT.rk3[q];
        } else if (t < T_TOTAL) {
            int q = t - B4; int tp = FT.tup4[q];
            int a = tp & 15, b = (tp >> 4) & 15, c = (tp >> 8) & 15, d = (tp >> 12) & 15;
            float s4v =
                W4P(a,b,c,d) + W4P(a,b,d,c) + W4P(a,c,b,d) + W4P(a,c,d,b) +
                W4P(a,d,b,c) + W4P(a,d,c,b) + W4P(b,a,c,d) + W4P(b,a,d,c) +
                W4P(b,c,a,d) + W4P(b,c,d,a) + W4P(b,d,a,c) + W4P(b,d,c,a) +
                W4P(c,a,b,d) + W4P(c,a,d,b) + W4P(c,b,a,d) + W4P(c,b,d,a) +
                W4P(c,d,a,b) + W4P(c,d,b,a) + W4P(d,a,b,c) + W4P(d,a,c,b) +
                W4P(d,b,a,c) + W4P(d,b,c,a) + W4P(d,c,a,b) + W4P(d,c,b,a);
            s = s4v * FT.rk4[q];
        }
        Wh[((t >> 3) * NO + o) * 8 + (t & 7)] = f2h(s);
    }
#undef W4P
#undef W3P
}

// ---------- MFMA GEMM: out[b,o] = sum_t M[t][b] * Wt[t][o], fp16 ----------
// Block: 32 b x 512 o (FULL O -- monomials generated once per b-row),
// 1024 threads (16 waves, each 32b x 32o, wO=wv: all o distinct), KT=64.
// Grid 256 = 1 block/CU. A fused-gen into swizzled double-buffered LDS.
__global__ __launch_bounds__(1024, 4) void pinet_gemm(
    const float* __restrict__ x, const ushort* __restrict__ Wh,
    float* __restrict__ out) {
    __shared__ float msm[32][93];           // per-b: {1, x0..x11, 78 deg2}
    __shared__ ushort Ash[2][32][8][8];     // [buf][b][t-octet slot (swz)][8 fp16]

    const int tid = threadIdx.x;
    const int b0 = blockIdx.x * 32;

    for (int idx = tid; idx < 32 * 13; idx += 1024) {
        int b = idx / 13, j = idx % 13;
        msm[b][j] = (j == 0) ? 1.0f : x[(b0 + b) * 12 + (j - 1)];
    }
    __syncthreads();
    for (int idx = tid; idx < 32 * 78; idx += 1024) {
        int b = idx / 78, q = idx % 78;
        uint32_t m2 = MP.v[B2 + q];
        msm[b][13 + q] = msm[b][m2 & 0xFFFFu] * msm[b][m2 >> 16];
    }

    const int l = tid & 63, wv = tid >> 6;  // 16 waves, wO = wv (512 o total)
    const int lm = l & 15, lg = l >> 4;
    const int o_w = wv * 32;
    const int bgen = tid & 31;
    const int task = tid >> 5;              // 0..31, 2 t's each
    const int sA = (task >> 2) ^ (bgen & 7);
    const int hOf = (task & 3) * 2;

    f32x4 acc[2][2] = {};
    f16x8 B0[2][2], B1[2][2];               // [os][chunk]

    auto gen = [&](int kt, int buf) {
        int t0 = kt * 64 + task * 2;
        uint2 mq = *(const uint2*)&MP.v[t0];
        const float* row = msm[bgen];
        float p0 = row[mq.x & 0xFFFFu] * row[mq.x >> 16];
        float p1 = row[mq.y & 0xFFFFu] * row[mq.y >> 16];
        ushort2 v = {f2h(p0), f2h(p1)};
        *(ushort2*)&Ash[buf][bgen][sA][hOf] = v;
    };
    auto loadB = [&](int kt, f16x8 (&B)[2][2]) {
#pragma unroll
        for (int os = 0; os < 2; ++os)
#pragma unroll
            for (int c = 0; c < 2; ++c) {
                int pk = kt * 8 + c * 4 + lg;
                B[os][c] = *(const f16x8*)(Wh + (pk * NO + o_w + os * 16 + lm) * 8);
            }
    };
    auto mfmaR = [&](int cur, f16x8 (&B)[2][2]) {
#pragma unroll
        for (int c = 0; c < 2; ++c) {
            f16x8 a[2];
#pragma unroll
            for (int bs = 0; bs < 2; ++bs) {
                int br = bs * 16 + lm;
                a[bs] = *(const f16x8*)&Ash[cur][br][(c * 4 + lg) ^ (br & 7)][0];
            }
#pragma unroll
            for (int bs = 0; bs < 2; ++bs)
#pragma unroll
                for (int os = 0; os < 2; ++os)
                    acc[bs][os] = MFMA16(a[bs], B[os][c], acc[bs][os]);
        }
    };

    __syncthreads();          // msm ready
    gen(0, 0);
    loadB(0, B0);
    __syncthreads();          // Ash[0] ready

    for (int kt2 = 0; kt2 < 28; kt2 += 2) {
        loadB(kt2 + 1, B1);
        gen(kt2 + 1, 1);
        mfmaR(0, B0);
        __syncthreads();
        loadB(kt2 + 2, B0);   // kt2+2 <= 28 < NKT always
        gen(kt2 + 2, 0);
        mfmaR(1, B1);
        __syncthreads();
    }
    mfmaR(0, B0);             // kt = 28

#pragma unroll
    for (int bs = 0; bs < 2; ++bs)
#pragma unroll
        for (int os = 0; os < 2; ++os) {
            int ob = o_w + os * 16 + lm;
#pragma unroll
            for (int r = 0; r < 4; ++r) {
                int bb = b0 + bs * 16 + lg * 4 + r;
                out[bb * NO + ob] = acc[bs][os][r];
            }
        }
}

extern "C" void kernel_launch(void* const* d_in, const int* in_sizes, int n_in,
                              void* d_out, int out_size, void* d_ws, size_t ws_size,
                              hipStream_t stream) {
    const float* x  = (const float*)d_in[0];
    const float* w0 = (const float*)d_in[1];
    const float* w1 = (const float*)d_in[2];
    const float* w2 = (const float*)d_in[3];
    const float* w3 = (const float*)d_in[4];
    const float* w4 = (const float*)d_in[5];
    float* out = (float*)d_out;

    ushort* Wh = (ushort*)d_ws;            // 232*512*8*2 = 1,900,544 B

    pinet_fold<<<NO, 1024, 0, stream>>>(w0, w1, w2, w3, w4, Wh);
    pinet_gemm<<<NB / 32, 1024, 0, stream>>>(x, Wh, out);
}